// Round 3
// baseline (33894.385 us; speedup 1.0000x reference)
//
#include <hip/hip_runtime.h>
#include <stdint.h>

// ---------------- constants ----------------
#define HID   1024          // H
#define B3H   3072          // 3H
#define BSZ   256           // batch
#define TLEN  128           // seq len
#define VOC   512
#define EMB   512

typedef unsigned short u16;
typedef short bf16x8 __attribute__((ext_vector_type(8)));
typedef float f32x4  __attribute__((ext_vector_type(4)));

__device__ __forceinline__ float bf2f(u16 u) {
    union { float f; uint32_t i; } c; c.i = ((uint32_t)u) << 16; return c.f;
}
__device__ __forceinline__ u16 f2bf(float f) {
    union { float f; uint32_t i; } c; c.f = f;
    uint32_t u = c.i;
    return (u16)((u + 0x7FFFu + ((u >> 16) & 1u)) >> 16);   // RNE
}
__device__ __forceinline__ float sigm(float x)  { return 1.f / (1.f + __expf(-x)); }
__device__ __forceinline__ float tanhf_(float x) {
    float e = __expf(-2.f * fabsf(x));
    float r = (1.f - e) / (1.f + e);
    return x < 0.f ? -r : r;
}

// ---------------- tiny utility kernels ----------------
__global__ void k_convert(const float* __restrict__ in, u16* __restrict__ out, int n) {
    int i = (blockIdx.x * 256 + threadIdx.x) * 4;
    if (i >= n) return;
    float4 f = *(const float4*)(in + i);
    uint32_t lo = (uint32_t)f2bf(f.x) | ((uint32_t)f2bf(f.y) << 16);
    uint32_t hi = (uint32_t)f2bf(f.z) | ((uint32_t)f2bf(f.w) << 16);
    uint2 p; p.x = lo; p.y = hi;
    *(uint2*)(out + i) = p;
}
__global__ void k_zero_f32(float* p, int n) { int i = blockIdx.x * 256 + threadIdx.x; if (i < n) p[i] = 0.f; }
__global__ void k_zero_u16(u16* p, int n)   { int i = blockIdx.x * 256 + threadIdx.x; if (i < n) p[i] = 0;   }

// ---------------- MFMA tile helper (16x64 per wave) ----------------
template<int KLEN>
__device__ __forceinline__ void mfma16x64(const u16* __restrict__ Aw, int lda,
                                          const u16* __restrict__ Wt, int ldb,
                                          f32x4 acc[4], int lane) {
    const int r = lane & 15, g = lane >> 4;
    const u16* ap = Aw + (size_t)r * lda + g * 8;
    const u16* bp = Wt + (size_t)r * ldb + g * 8;
#pragma unroll 4
    for (int k = 0; k < KLEN; k += 32) {
        bf16x8 a = *(const bf16x8*)(ap + k);
#pragma unroll
        for (int n = 0; n < 4; n++) {
            bf16x8 b = *(const bf16x8*)(bp + (size_t)(n * 16) * ldb + k);
            acc[n] = __builtin_amdgcn_mfma_f32_16x16x32_bf16(a, b, acc[n], 0, 0, 0);
        }
    }
}
__device__ __forceinline__ void store_f32(float* Cw, int ldc, const float* bias,
                                          const f32x4 acc[4], int lane) {
    int c = lane & 15, r0 = (lane >> 4) * 4;
#pragma unroll
    for (int n = 0; n < 4; n++)
#pragma unroll
        for (int r = 0; r < 4; r++) {
            float x = acc[n][r] + (bias ? bias[n * 16 + c] : 0.f);
            Cw[(size_t)(r0 + r) * ldc + n * 16 + c] = x;
        }
}

// ---------------- proj: X_all[t*B+b] = emb[tok] @ projW^T + projb (bf16 out) ----------------
__global__ void __launch_bounds__(256) k_proj(const u16* __restrict__ emb_bf, const u16* __restrict__ projW_bf,
                       const float* __restrict__ projb, const int* __restrict__ target,
                       u16* __restrict__ X_all) {
    int tn = blockIdx.x * 64, tm = blockIdx.y * 64;
    int wid = threadIdx.x >> 6, lane = threadIdx.x & 63;
    int rr = lane & 15, g = lane >> 4;
    int rowg = tm + wid * 16 + rr;
    int t = rowg >> 8, b = rowg & 255;
    int tok = (t == 0) ? 0 : target[b * TLEN + t - 1];
    const u16* ap = emb_bf + (size_t)tok * EMB + g * 8;
    f32x4 acc[4];
#pragma unroll
    for (int n = 0; n < 4; n++) for (int q = 0; q < 4; q++) acc[n][q] = 0.f;
#pragma unroll 4
    for (int k = 0; k < EMB; k += 32) {
        bf16x8 a = *(const bf16x8*)(ap + k);
#pragma unroll
        for (int n = 0; n < 4; n++) {
            bf16x8 bb = *(const bf16x8*)(projW_bf + (size_t)(tn + n * 16 + rr) * EMB + g * 8 + k);
            acc[n] = __builtin_amdgcn_mfma_f32_16x16x32_bf16(a, bb, acc[n], 0, 0, 0);
        }
    }
    int c = lane & 15, r0 = (lane >> 4) * 4;
    u16* Cw = X_all + (size_t)(tm + wid * 16) * HID + tn;
#pragma unroll
    for (int n = 0; n < 4; n++)
#pragma unroll
        for (int q = 0; q < 4; q++)
            Cw[(size_t)(r0 + q) * HID + n * 16 + c] = f2bf(acc[n][q] + projb[tn + n * 16 + c]);
}

// ---------------- standalone GEMM (prologue gi0[t=0]) ----------------
__global__ void __launch_bounds__(256) k_gemm0(const u16* __restrict__ A, const u16* __restrict__ W,
                                               float* __restrict__ C) {
    int tn = blockIdx.x * 64, tm = blockIdx.y * 64;
    int wid = threadIdx.x >> 6, lane = threadIdx.x & 63;
    f32x4 acc[4];
#pragma unroll
    for (int n = 0; n < 4; n++) for (int q = 0; q < 4; q++) acc[n][q] = 0.f;
    mfma16x64<HID>(A + (size_t)(tm + wid * 16) * HID, HID, W + (size_t)tn * HID, HID, acc, lane);
    store_f32(C + (size_t)(tm + wid * 16) * B3H + tn, B3H, nullptr, acc, lane);
}

// ================= persistent recurrence kernel =================
// 256 blocks x 512 threads = 2048 waves. 5 device barriers/step.
// Phases (step t):
//  Q0: ew0 (waves 0..255)      || gh2  = h2_bf  @ Whh2  (for this step's Q4)
//  Q1: gi1 = h0_bf @ Wih1      || gi0' = X[t+1] @ Wih0  (for next step's Q0)
//  Q2: ew1                     || gh0' = h0_bf  @ Whh0  (for next step)
//  Q3: gi2 = h1_bf @ Wih2
//  Q4: ew2 (writes H2 into X_all[t]) || gh1' = h1_bf @ Whh1 (for next step)

__device__ __forceinline__ void gbar(uint32_t* bar, uint32_t& tgt) {
    tgt += 256;                                  // grid size
    __syncthreads();                             // all block stores drained to L2
    if (threadIdx.x == 0) {
        __threadfence();                         // agent release: wbl2 -> device-visible
        __hip_atomic_fetch_add(bar, 1u, __ATOMIC_RELAXED, __HIP_MEMORY_SCOPE_AGENT);
        while (__hip_atomic_load(bar, __ATOMIC_RELAXED, __HIP_MEMORY_SCOPE_AGENT) < tgt)
            __builtin_amdgcn_s_sleep(2);
        __threadfence();                         // agent acquire: inv L1/L2
    }
    __syncthreads();
}

// one wave handles one batch row: GRU gates + residual + LayerNorm (f32)
template<int GIK, int GHK>
__device__ __forceinline__ void ew_row(int b, int cell, int t,
    const float* __restrict__ giP, const float* __restrict__ ghP,
    const float* bih_all, const float* bhh_all,
    float* h_f32, u16* h_bf, u16* X_all,
    const float* ln_s_all, const float* ln_b_all, int lane) {
    const float* bih = bih_all + cell * B3H;
    const float* bhh = bhh_all + cell * B3H;
    const float* lns = ln_s_all + cell * HID;
    const float* lnb = ln_b_all + cell * HID;
    float* hrow = h_f32 + ((size_t)cell * BSZ + b) * HID;
    const size_t rowB = (size_t)b * B3H;
    float val[16], s = 0.f, s2 = 0.f;
#pragma unroll
    for (int e = 0; e < 4; e++) {
        int j = e * 256 + lane * 4;
        float gg[3][4], hh[3][4];
#pragma unroll
        for (int g = 0; g < 3; g++) {
            int o = g * HID + j;
            float4 a = *(const float4*)(bih + o);
#pragma unroll
            for (int p = 0; p < GIK; p++) {
                float4 q = *(const float4*)(giP + (size_t)p * (BSZ * (size_t)B3H) + rowB + o);
                a.x += q.x; a.y += q.y; a.z += q.z; a.w += q.w;
            }
            gg[g][0] = a.x; gg[g][1] = a.y; gg[g][2] = a.z; gg[g][3] = a.w;
            float4 h4 = *(const float4*)(bhh + o);
#pragma unroll
            for (int p = 0; p < GHK; p++) {
                float4 q = *(const float4*)(ghP + (size_t)p * (BSZ * (size_t)B3H) + rowB + o);
                h4.x += q.x; h4.y += q.y; h4.z += q.z; h4.w += q.w;
            }
            hh[g][0] = h4.x; hh[g][1] = h4.y; hh[g][2] = h4.z; hh[g][3] = h4.w;
        }
        float4 hp = *(const float4*)(hrow + j);
        float hpv[4] = {hp.x, hp.y, hp.z, hp.w};
        float xv[4];
        if (cell == 0) {
            ushort4 u = *(const ushort4*)(X_all + ((size_t)t * BSZ + b) * HID + j);
            xv[0] = bf2f(u.x); xv[1] = bf2f(u.y); xv[2] = bf2f(u.z); xv[3] = bf2f(u.w);
        } else {
            float4 x4 = *(const float4*)(h_f32 + ((size_t)(cell - 1) * BSZ + b) * HID + j);
            xv[0] = x4.x; xv[1] = x4.y; xv[2] = x4.z; xv[3] = x4.w;
        }
#pragma unroll
        for (int q = 0; q < 4; q++) {
            float r = sigm(gg[0][q] + hh[0][q]);
            float z = sigm(gg[1][q] + hh[1][q]);
            float n = tanhf_(gg[2][q] + r * hh[2][q]);
            float v = (1.f - z) * n + z * hpv[q] + xv[q];
            val[e * 4 + q] = v; s += v; s2 += v * v;
        }
    }
#pragma unroll
    for (int o = 32; o > 0; o >>= 1) { s += __shfl_xor(s, o); s2 += __shfl_xor(s2, o); }
    float mu = s * (1.f / HID);
    float inv = rsqrtf(s2 * (1.f / HID) - mu * mu + 1e-5f);
    u16* hbrow = h_bf + ((size_t)cell * BSZ + b) * HID;
#pragma unroll
    for (int e = 0; e < 4; e++) {
        int j = e * 256 + lane * 4;
        float4 sc = *(const float4*)(lns + j);
        float4 bi = *(const float4*)(lnb + j);
        float o0 = (val[e * 4 + 0] - mu) * inv * sc.x + bi.x;
        float o1 = (val[e * 4 + 1] - mu) * inv * sc.y + bi.y;
        float o2 = (val[e * 4 + 2] - mu) * inv * sc.z + bi.z;
        float o3 = (val[e * 4 + 3] - mu) * inv * sc.w + bi.w;
        float4 of; of.x = o0; of.y = o1; of.z = o2; of.w = o3;
        *(float4*)(hrow + j) = of;
        ushort4 ub; ub.x = f2bf(o0); ub.y = f2bf(o1); ub.z = f2bf(o2); ub.w = f2bf(o3);
        *(ushort4*)(hbrow + j) = ub;
        if (cell == 2)
            *(ushort4*)(X_all + ((size_t)t * BSZ + b) * HID + j) = ub;  // slot consumed -> H2_all
    }
}

// GEMM job: [256,1024(bf16)] @ W[3072,1024]^T tile. 8 waves of a block share one B-strip.
// KS=1: strips s in [0,96): tn=s%48, tm=(s/48)*8+w, K=1024.
// KS=2: strips s in [0,192): tn=s%48, kc=(s/48)&1, tm=((s/48)>>1)*8+w, K=512, out slab kc.
template<int KS>
__device__ __forceinline__ void gemm_job(int idx, const u16* __restrict__ A,
                                         const u16* __restrict__ W, float* __restrict__ P, int lane) {
    constexpr int KL = (KS == 2) ? 512 : 1024;
    int w = idx & 7, s = idx >> 3;
    int tn = s % 48, seg = s / 48;
    int kc  = (KS == 2) ? (seg & 1) : 0;
    int tmh = (KS == 2) ? (seg >> 1) : seg;
    int tm = tmh * 8 + w;
    const int r = lane & 15, g = lane >> 4;
    const u16* ap = A + (size_t)(tm * 16 + r) * HID + kc * KL + g * 8;
    const u16* bp = W + (size_t)(tn * 64 + r) * HID + kc * KL + g * 8;
    f32x4 acc[4];
#pragma unroll
    for (int n = 0; n < 4; n++) for (int q = 0; q < 4; q++) acc[n][q] = 0.f;
#pragma unroll 4
    for (int k = 0; k < KL; k += 32) {
        bf16x8 a = *(const bf16x8*)(ap + k);
#pragma unroll
        for (int n = 0; n < 4; n++) {
            bf16x8 b = *(const bf16x8*)(bp + (size_t)(n * 16) * HID + k);
            acc[n] = __builtin_amdgcn_mfma_f32_16x16x32_bf16(a, b, acc[n], 0, 0, 0);
        }
    }
    float* Cw = P + (size_t)kc * (BSZ * (size_t)B3H) + (size_t)(tm * 16) * B3H + tn * 64;
    int c = lane & 15, r0 = (lane >> 4) * 4;
#pragma unroll
    for (int n = 0; n < 4; n++)
#pragma unroll
        for (int q = 0; q < 4; q++)
            Cw[(size_t)(r0 + q) * B3H + n * 16 + c] = acc[n][q];
}

template<int KS>
__global__ void __launch_bounds__(512) k_loop(
    u16* __restrict__ X_all, u16* __restrict__ h_bf, float* __restrict__ h_f32,
    const u16* __restrict__ Wih, const u16* __restrict__ Whh,
    const float* __restrict__ bih, const float* __restrict__ bhh,
    const float* __restrict__ ln_s, const float* __restrict__ ln_b,
    float* __restrict__ gi0P, float* __restrict__ giXP,
    float* __restrict__ gh0P, float* __restrict__ gh1P, float* __restrict__ gh2P,
    uint32_t* bar) {
    constexpr int NGW = (KS == 2) ? 1536 : 768;     // waves per (possibly split) GEMM
    const size_t SL = (size_t)BSZ * B3H;
    int wid = threadIdx.x >> 6, lane = threadIdx.x & 63;
    int gw = blockIdx.x * 8 + wid;
    uint32_t tgt = 0;

    for (int t = 0; t < TLEN; t++) {
        // ---- Q0: ew0 || gh2 = h2_bf @ Whh2
        if (gw < 256)
            ew_row<1, KS>(gw, 0, t, gi0P + (size_t)(t & 1) * SL, gh0P,
                          bih, bhh, h_f32, h_bf, X_all, ln_s, ln_b, lane);
        else if (gw < 256 + NGW)
            gemm_job<KS>(gw - 256, h_bf + 2 * (size_t)BSZ * HID, Whh + 2 * (size_t)B3H * HID, gh2P, lane);
        gbar(bar, tgt);
        // ---- Q1: gi1 = h0 @ Wih1 || gi0' = X[t+1] @ Wih0
        if (gw < 768)
            gemm_job<1>(gw, h_bf, Wih + (size_t)B3H * HID, giXP, lane);
        else if (gw < 1536 && t + 1 < TLEN)
            gemm_job<1>(gw - 768, X_all + (size_t)(t + 1) * BSZ * HID, Wih,
                        gi0P + (size_t)((t + 1) & 1) * SL, lane);
        gbar(bar, tgt);
        // ---- Q2: ew1 || gh0' = h0 @ Whh0 (next step)
        if (gw < 256)
            ew_row<1, KS>(gw, 1, t, giXP, gh1P, bih, bhh, h_f32, h_bf, X_all, ln_s, ln_b, lane);
        else if (gw < 256 + NGW)
            gemm_job<KS>(gw - 256, h_bf, Whh, gh0P, lane);
        gbar(bar, tgt);
        // ---- Q3: gi2 = h1 @ Wih2
        if (gw < NGW)
            gemm_job<KS>(gw, h_bf + (size_t)BSZ * HID, Wih + 2 * (size_t)B3H * HID, giXP, lane);
        gbar(bar, tgt);
        // ---- Q4: ew2 (writes H2 into X_all[t]) || gh1' = h1 @ Whh1 (next step)
        if (gw < 256)
            ew_row<KS, KS>(gw, 2, t, giXP, gh2P, bih, bhh, h_f32, h_bf, X_all, ln_s, ln_b, lane);
        else if (gw < 256 + NGW)
            gemm_job<KS>(gw - 256, h_bf + (size_t)BSZ * HID, Whh + (size_t)B3H * HID, gh1P, lane);
        gbar(bar, tgt);
    }
}

// ---------------- batched tail: fc1 (relu, bf16 out) ----------------
__global__ void __launch_bounds__(256) k_fc1b(const u16* __restrict__ A, const u16* __restrict__ W,
                       const float* __restrict__ bias, u16* __restrict__ C) {
    int tn = blockIdx.x * 64, tm = blockIdx.y * 64;
    int wid = threadIdx.x >> 6, lane = threadIdx.x & 63;
    f32x4 acc[4];
#pragma unroll
    for (int n = 0; n < 4; n++) for (int q = 0; q < 4; q++) acc[n][q] = 0.f;
    mfma16x64<HID>(A + (size_t)(tm + wid * 16) * HID, HID, W + (size_t)tn * HID, HID, acc, lane);
    int c = lane & 15, r0 = (lane >> 4) * 4;
    u16* Cw = C + (size_t)(tm + wid * 16) * 2048 + tn;
#pragma unroll
    for (int n = 0; n < 4; n++)
#pragma unroll
        for (int q = 0; q < 4; q++) {
            float x = acc[n][q] + bias[tn + n * 16 + c];
            Cw[(size_t)(r0 + q) * 2048 + n * 16 + c] = f2bf(fmaxf(x, 0.f));
        }
}

// ---------------- batched tail: fc2 (+bias, f32 out) ----------------
__global__ void __launch_bounds__(256) k_fc2b(const u16* __restrict__ A, const u16* __restrict__ W,
                       const float* __restrict__ bias, float* __restrict__ C) {
    int tn = blockIdx.x * 64, tm = blockIdx.y * 64;
    int wid = threadIdx.x >> 6, lane = threadIdx.x & 63;
    f32x4 acc[4];
#pragma unroll
    for (int n = 0; n < 4; n++) for (int q = 0; q < 4; q++) acc[n][q] = 0.f;
    mfma16x64<2048>(A + (size_t)(tm + wid * 16) * 2048, 2048, W + (size_t)tn * 2048, 2048, acc, lane);
    store_f32(C + (size_t)(tm + wid * 16) * VOC + tn, VOC, bias + tn, acc, lane);
}

// ---------------- logsumexp + target gather -> LP[t][b] ----------------
__global__ void __launch_bounds__(256) k_lse2(const float* __restrict__ part, const int* __restrict__ target,
                       int c0, float* __restrict__ LP) {
    int wid = threadIdx.x >> 6, lane = threadIdx.x & 63;
    int r = blockIdx.x * 4 + wid;
    const float* row = part + (size_t)r * VOC;
    float v[8];
#pragma unroll
    for (int e = 0; e < 8; e++) v[e] = row[e * 64 + lane];
    float m = v[0];
#pragma unroll
    for (int e = 1; e < 8; e++) m = fmaxf(m, v[e]);
    for (int o = 32; o > 0; o >>= 1) m = fmaxf(m, __shfl_xor(m, o));
    float s = 0.f;
#pragma unroll
    for (int e = 0; e < 8; e++) s += __expf(v[e] - m);
    for (int o = 32; o > 0; o >>= 1) s += __shfl_xor(s, o);
    int t = c0 + (r >> 8), b = r & 255;
    int tg = target[b * TLEN + t];
    float tv = 0.f;
#pragma unroll
    for (int e = 0; e < 8; e++) if (e * 64 + lane == tg) tv = v[e];
    for (int o = 32; o > 0; o >>= 1) tv += __shfl_xor(tv, o);
    if (lane == 0) LP[(size_t)t * BSZ + b] = tv - (m + logf(s));
}

// ---------------- final: out[b] = sum_t LP[t][b] ----------------
__global__ void k_out(const float* __restrict__ LP, float* __restrict__ out) {
    int b = threadIdx.x;
    float s = 0.f;
    for (int t = 0; t < TLEN; t++) s += LP[(size_t)t * BSZ + b];
    out[b] = s;
}

// ---------------- host ----------------
extern "C" void kernel_launch(void* const* d_in, const int* in_sizes, int n_in,
                              void* d_out, int out_size, void* d_ws, size_t ws_size,
                              hipStream_t stream) {
    const int*   target = (const int*)  d_in[0];
    const float* emb    = (const float*)d_in[1];
    const float* projW  = (const float*)d_in[2];
    const float* projb  = (const float*)d_in[3];
    const float* gWih   = (const float*)d_in[4];
    const float* gWhh   = (const float*)d_in[5];
    const float* gbih   = (const float*)d_in[6];
    const float* gbhh   = (const float*)d_in[7];
    const float* ln_s   = (const float*)d_in[8];
    const float* ln_b   = (const float*)d_in[9];
    const float* fc1W   = (const float*)d_in[10];
    const float* fc1b   = (const float*)d_in[11];
    const float* fc2W   = (const float*)d_in[12];
    const float* fc2b   = (const float*)d_in[13];
    float* out = (float*)d_out;

    char* ws = (char*)d_ws;
    size_t off = 0;
    auto alloc = [&](size_t bytes) { void* p = ws + off; off += (bytes + 511) & ~511ull; return p; };
    u16* emb_bf   = (u16*)alloc((size_t)VOC * EMB * 2);
    u16* projW_bf = (u16*)alloc((size_t)HID * EMB * 2);
    u16* Wih_bf   = (u16*)alloc((size_t)3 * B3H * HID * 2);
    u16* Whh_bf   = (u16*)alloc((size_t)3 * B3H * HID * 2);
    u16* fc1W_bf  = (u16*)alloc((size_t)2048 * HID * 2);
    u16* fc2W_bf  = (u16*)alloc((size_t)VOC * 2048 * 2);
    u16* X_all    = (u16*)alloc((size_t)TLEN * BSZ * HID * 2);   // becomes H2_all as loop consumes it
    float* h_f32  = (float*)alloc((size_t)3 * BSZ * HID * 4);
    u16* h_bf     = (u16*)alloc((size_t)3 * BSZ * HID * 2);
    float* LP     = (float*)alloc((size_t)TLEN * BSZ * 4);
    uint32_t* bar = (uint32_t*)alloc(512);

    // KS=2 (K-split gh/gi2 GEMMs) iff workspace allows; KS=1 fits proven ws floor.
    const size_t SLB = (size_t)BSZ * B3H * 4;         // 3 MB slab
    int KS = (ws_size >= off + 10 * SLB) ? 2 : 1;
    float* gi0P = (float*)alloc(2 * SLB);             // 2 time-slots (unsplit)
    float* giXP = (float*)alloc((size_t)KS * SLB);    // gi1 (slab0) / gi2 (KS slabs)
    float* gh0P = (float*)alloc((size_t)KS * SLB);
    float* gh1P = (float*)alloc((size_t)KS * SLB);
    float* gh2P = (float*)alloc((size_t)KS * SLB);
    if (off > ws_size) return;
    int CH = (KS == 2) ? 16 : 8;                      // tail chunk; overlays loop partials
    u16*   a1c   = (u16*)gi0P;
    float* partc = (float*)((char*)gi0P + (size_t)CH * BSZ * 2048 * 2);

    auto cvt = [&](const float* s, u16* d, int n) {
        k_convert<<<dim3((n / 4 + 255) / 256), 256, 0, stream>>>(s, d, n);
    };
    cvt(emb,   emb_bf,   VOC * EMB);
    cvt(projW, projW_bf, HID * EMB);
    cvt(gWih,  Wih_bf,   3 * B3H * HID);
    cvt(gWhh,  Whh_bf,   3 * B3H * HID);
    cvt(fc1W,  fc1W_bf,  2048 * HID);
    cvt(fc2W,  fc2W_bf,  VOC * 2048);
    k_zero_f32<<<dim3((3 * BSZ * HID + 255) / 256), 256, 0, stream>>>(h_f32, 3 * BSZ * HID);
    k_zero_u16<<<dim3((3 * BSZ * HID + 255) / 256), 256, 0, stream>>>(h_bf, 3 * BSZ * HID);
    {
        int n = KS * BSZ * B3H;
        k_zero_f32<<<dim3((n + 255) / 256), 256, 0, stream>>>(gh0P, n);
        k_zero_f32<<<dim3((n + 255) / 256), 256, 0, stream>>>(gh1P, n);
    }
    k_zero_f32<<<dim3(1), 256, 0, stream>>>((float*)bar, 1);

    // X_all[t*B+b] = emb[tok] @ projW^T + projb
    k_proj<<<dim3(HID / 64, (TLEN * BSZ) / 64), 256, 0, stream>>>(emb_bf, projW_bf, projb, target, X_all);
    // gi0 for t=0
    k_gemm0<<<dim3(B3H / 64, BSZ / 64), 256, 0, stream>>>(X_all, Wih_bf, gi0P);

    // the whole recurrence: one persistent kernel, 640 device barriers
    if (KS == 2)
        k_loop<2><<<dim3(256), 512, 0, stream>>>(X_all, h_bf, h_f32, Wih_bf, Whh_bf, gbih, gbhh,
                                                 ln_s, ln_b, gi0P, giXP, gh0P, gh1P, gh2P, bar);
    else
        k_loop<1><<<dim3(256), 512, 0, stream>>>(X_all, h_bf, h_f32, Wih_bf, Whh_bf, gbih, gbhh,
                                                 ln_s, ln_b, gi0P, giXP, gh0P, gh1P, gh2P, bar);

    // batched tail over T in chunks: fc1 -> fc2 -> log-softmax
    for (int c0 = 0; c0 < TLEN; c0 += CH) {
        int M = CH * BSZ;
        const u16* Ain = X_all + (size_t)c0 * BSZ * HID;   // H2 rows for steps [c0, c0+CH)
        k_fc1b<<<dim3(2048 / 64, M / 64), 256, 0, stream>>>(Ain, fc1W_bf, fc1b, a1c);
        k_fc2b<<<dim3(VOC / 64, M / 64), 256, 0, stream>>>(a1c, fc2W_bf, fc2b, partc);
        k_lse2<<<dim3(M / 4), 256, 0, stream>>>(partc, target, c0, LP);
    }
    k_out<<<1, 256, 0, stream>>>(LP, out);
}

// Round 4
// 14966.487 us; speedup vs baseline: 2.2647x; 2.2647x over previous
//
#include <hip/hip_runtime.h>
#include <stdint.h>

// ---------------- constants ----------------
#define HID   1024          // H
#define B3H   3072          // 3H
#define BSZ   256           // batch
#define TLEN  128           // seq len
#define VOC   512
#define EMB   512
#define SLAB  ((size_t)BSZ * B3H)    // one [256,3072] f32 slab (elements)

typedef unsigned short u16;
typedef short bf16x8 __attribute__((ext_vector_type(8)));
typedef float f32x4  __attribute__((ext_vector_type(4)));

__device__ __forceinline__ float bf2f(u16 u) {
    union { float f; uint32_t i; } c; c.i = ((uint32_t)u) << 16; return c.f;
}
__device__ __forceinline__ u16 f2bf(float f) {
    union { float f; uint32_t i; } c; c.f = f;
    uint32_t u = c.i;
    return (u16)((u + 0x7FFFu + ((u >> 16) & 1u)) >> 16);   // RNE
}
__device__ __forceinline__ float sigm(float x)  { return 1.f / (1.f + __expf(-x)); }
__device__ __forceinline__ float tanhf_(float x) {
    float e = __expf(-2.f * fabsf(x));
    float r = (1.f - e) / (1.f + e);
    return x < 0.f ? -r : r;
}

// ---------------- tiny utility kernels ----------------
__global__ void k_convert(const float* __restrict__ in, u16* __restrict__ out, int n) {
    int i = (blockIdx.x * 256 + threadIdx.x) * 4;
    if (i >= n) return;
    float4 f = *(const float4*)(in + i);
    uint32_t lo = (uint32_t)f2bf(f.x) | ((uint32_t)f2bf(f.y) << 16);
    uint32_t hi = (uint32_t)f2bf(f.z) | ((uint32_t)f2bf(f.w) << 16);
    uint2 p; p.x = lo; p.y = hi;
    *(uint2*)(out + i) = p;
}

// ---------------- MFMA tile helper (16x64 per wave) ----------------
template<int KLEN>
__device__ __forceinline__ void mfma16x64(const u16* __restrict__ Aw, int lda,
                                          const u16* __restrict__ Wt, int ldb,
                                          f32x4 acc[4], int lane) {
    const int r = lane & 15, g = lane >> 4;
    const u16* ap = Aw + (size_t)r * lda + g * 8;
    const u16* bp = Wt + (size_t)r * ldb + g * 8;
#pragma unroll 4
    for (int k = 0; k < KLEN; k += 32) {
        bf16x8 a = *(const bf16x8*)(ap + k);
#pragma unroll
        for (int n = 0; n < 4; n++) {
            bf16x8 b = *(const bf16x8*)(bp + (size_t)(n * 16) * ldb + k);
            acc[n] = __builtin_amdgcn_mfma_f32_16x16x32_bf16(a, b, acc[n], 0, 0, 0);
        }
    }
}
__device__ __forceinline__ void store_f32(float* Cw, int ldc, const float* bias,
                                          const f32x4 acc[4], int lane) {
    int c = lane & 15, r0 = (lane >> 4) * 4;
#pragma unroll
    for (int n = 0; n < 4; n++)
#pragma unroll
        for (int r = 0; r < 4; r++) {
            float x = acc[n][r] + (bias ? bias[n * 16 + c] : 0.f);
            Cw[(size_t)(r0 + r) * ldc + n * 16 + c] = x;
        }
}

// ---------------- proj: X_all[t*B+b] = emb[tok] @ projW^T + projb (bf16 out) ----------------
__global__ void __launch_bounds__(256) k_proj(const u16* __restrict__ emb_bf, const u16* __restrict__ projW_bf,
                       const float* __restrict__ projb, const int* __restrict__ target,
                       u16* __restrict__ X_all) {
    int tn = blockIdx.x * 64, tm = blockIdx.y * 64;
    int wid = threadIdx.x >> 6, lane = threadIdx.x & 63;
    int rr = lane & 15, g = lane >> 4;
    int rowg = tm + wid * 16 + rr;
    int t = rowg >> 8, b = rowg & 255;
    int tok = (t == 0) ? 0 : target[b * TLEN + t - 1];
    const u16* ap = emb_bf + (size_t)tok * EMB + g * 8;
    f32x4 acc[4];
#pragma unroll
    for (int n = 0; n < 4; n++) for (int q = 0; q < 4; q++) acc[n][q] = 0.f;
#pragma unroll 4
    for (int k = 0; k < EMB; k += 32) {
        bf16x8 a = *(const bf16x8*)(ap + k);
#pragma unroll
        for (int n = 0; n < 4; n++) {
            bf16x8 bb = *(const bf16x8*)(projW_bf + (size_t)(tn + n * 16 + rr) * EMB + g * 8 + k);
            acc[n] = __builtin_amdgcn_mfma_f32_16x16x32_bf16(a, bb, acc[n], 0, 0, 0);
        }
    }
    int c = lane & 15, r0 = (lane >> 4) * 4;
    u16* Cw = X_all + (size_t)(tm + wid * 16) * HID + tn;
#pragma unroll
    for (int n = 0; n < 4; n++)
#pragma unroll
        for (int q = 0; q < 4; q++)
            Cw[(size_t)(r0 + q) * HID + n * 16 + c] = f2bf(acc[n][q] + projb[tn + n * 16 + c]);
}

// ============== wavefront GEMM: 6 groups (gi0..2, gh0..2) ==============
// wave index wv: cell c processes t = wv - c.
// A sources read h_bf slot rd=(wv+1)&1 (written by previous wave's ew).
// z = 0..2 : gi_c  (A = X_all[t] for c==0 else h_bf[rd][c-1];  W = Wih[c])
// z = 3..5 : gh_c  (A = h_bf[rd][c];                           W = Whh[c])
__global__ void __launch_bounds__(256) k_wgemm(int wv,
    const u16* __restrict__ X_all, const u16* __restrict__ h_bf,
    const u16* __restrict__ Wih, const u16* __restrict__ Whh,
    float* __restrict__ giP, float* __restrict__ ghP) {
    int z = blockIdx.z;
    int cell = (z >= 3) ? z - 3 : z;
    bool isgh = (z >= 3);
    int t = wv - cell;
    if (t < 0 || t >= TLEN) return;
    int rd = (wv + 1) & 1;
    const u16* A;
    if (isgh)            A = h_bf + (size_t)(rd * 3 + cell)     * BSZ * HID;
    else if (cell == 0)  A = X_all + (size_t)t * BSZ * HID;
    else                 A = h_bf + (size_t)(rd * 3 + cell - 1) * BSZ * HID;
    const u16* W = (isgh ? Whh : Wih) + (size_t)cell * B3H * HID;
    float*     C = (isgh ? ghP : giP) + (size_t)cell * SLAB;

    int tn = blockIdx.x * 64, tm = blockIdx.y * 64;
    int wid = threadIdx.x >> 6, lane = threadIdx.x & 63;
    f32x4 acc[4];
#pragma unroll
    for (int n = 0; n < 4; n++) for (int q = 0; q < 4; q++) acc[n][q] = 0.f;
    mfma16x64<HID>(A + (size_t)(tm + wid * 16) * HID, HID, W + (size_t)tn * HID, HID, acc, lane);
    store_f32(C + (size_t)(tm + wid * 16) * B3H + tn, B3H, nullptr, acc, lane);
}

// ============== wavefront ew: 3 cells, 1 wave per batch row ==============
__global__ void __launch_bounds__(256) k_wew(int wv,
    const float* __restrict__ giP, const float* __restrict__ ghP,
    const float* __restrict__ bih_all, const float* __restrict__ bhh_all,
    float* __restrict__ h_f32, u16* __restrict__ h_bf, u16* __restrict__ X_all,
    const float* __restrict__ ln_s_all, const float* __restrict__ ln_b_all) {
    int cell = blockIdx.y;
    int t = wv - cell;
    if (t < 0 || t >= TLEN) return;
    int wid = threadIdx.x >> 6, lane = threadIdx.x & 63;
    int b = blockIdx.x * 4 + wid;
    int rd = (wv + 1) & 1, wr = wv & 1;

    const float* gi  = giP + (size_t)cell * SLAB + (size_t)b * B3H;
    const float* gh  = ghP + (size_t)cell * SLAB + (size_t)b * B3H;
    const float* bih = bih_all + cell * B3H;
    const float* bhh = bhh_all + cell * B3H;
    const float* lns = ln_s_all + cell * HID;
    const float* lnb = ln_b_all + cell * HID;
    const float* hprev = h_f32 + ((size_t)(rd * 3 + cell) * BSZ + b) * HID;
    float*       hout  = h_f32 + ((size_t)(wr * 3 + cell) * BSZ + b) * HID;
    u16*         hbout = h_bf  + ((size_t)(wr * 3 + cell) * BSZ + b) * HID;
    const float* xsrcf = (cell > 0) ? h_f32 + ((size_t)(rd * 3 + cell - 1) * BSZ + b) * HID : nullptr;
    const u16*   xsrcb = X_all + ((size_t)t * BSZ + b) * HID;

    float val[16], s = 0.f, s2 = 0.f;
#pragma unroll
    for (int e = 0; e < 4; e++) {
        int j = e * 256 + lane * 4;
        float gg[3][4], hh[3][4];
#pragma unroll
        for (int g = 0; g < 3; g++) {
            int o = g * HID + j;
            float4 a = *(const float4*)(gi + o);
            float4 ab = *(const float4*)(bih + o);
            gg[g][0] = a.x + ab.x; gg[g][1] = a.y + ab.y; gg[g][2] = a.z + ab.z; gg[g][3] = a.w + ab.w;
            float4 h4 = *(const float4*)(gh + o);
            float4 hb = *(const float4*)(bhh + o);
            hh[g][0] = h4.x + hb.x; hh[g][1] = h4.y + hb.y; hh[g][2] = h4.z + hb.z; hh[g][3] = h4.w + hb.w;
        }
        float4 hp = *(const float4*)(hprev + j);
        float hpv[4] = {hp.x, hp.y, hp.z, hp.w};
        float xv[4];
        if (cell == 0) {
            ushort4 u = *(const ushort4*)(xsrcb + j);
            xv[0] = bf2f(u.x); xv[1] = bf2f(u.y); xv[2] = bf2f(u.z); xv[3] = bf2f(u.w);
        } else {
            float4 x4 = *(const float4*)(xsrcf + j);
            xv[0] = x4.x; xv[1] = x4.y; xv[2] = x4.z; xv[3] = x4.w;
        }
#pragma unroll
        for (int q = 0; q < 4; q++) {
            float r = sigm(gg[0][q] + hh[0][q]);
            float z = sigm(gg[1][q] + hh[1][q]);
            float n = tanhf_(gg[2][q] + r * hh[2][q]);
            float v = (1.f - z) * n + z * hpv[q] + xv[q];
            val[e * 4 + q] = v; s += v; s2 += v * v;
        }
    }
#pragma unroll
    for (int o = 32; o > 0; o >>= 1) { s += __shfl_xor(s, o); s2 += __shfl_xor(s2, o); }
    float mu = s * (1.f / HID);
    float inv = rsqrtf(s2 * (1.f / HID) - mu * mu + 1e-5f);
#pragma unroll
    for (int e = 0; e < 4; e++) {
        int j = e * 256 + lane * 4;
        float4 sc = *(const float4*)(lns + j);
        float4 bi = *(const float4*)(lnb + j);
        float o0 = (val[e * 4 + 0] - mu) * inv * sc.x + bi.x;
        float o1 = (val[e * 4 + 1] - mu) * inv * sc.y + bi.y;
        float o2 = (val[e * 4 + 2] - mu) * inv * sc.z + bi.z;
        float o3 = (val[e * 4 + 3] - mu) * inv * sc.w + bi.w;
        float4 of; of.x = o0; of.y = o1; of.z = o2; of.w = o3;
        *(float4*)(hout + j) = of;
        ushort4 ub; ub.x = f2bf(o0); ub.y = f2bf(o1); ub.z = f2bf(o2); ub.w = f2bf(o3);
        *(ushort4*)(hbout + j) = ub;
        if (cell == 2)
            *(ushort4*)(X_all + ((size_t)t * BSZ + b) * HID + j) = ub;  // slot t consumed at wave t -> H2_all
    }
}

// ---------------- batched tail: fc1 (relu, bf16 out) ----------------
__global__ void __launch_bounds__(256) k_fc1b(const u16* __restrict__ A, const u16* __restrict__ W,
                       const float* __restrict__ bias, u16* __restrict__ C) {
    int tn = blockIdx.x * 64, tm = blockIdx.y * 64;
    int wid = threadIdx.x >> 6, lane = threadIdx.x & 63;
    f32x4 acc[4];
#pragma unroll
    for (int n = 0; n < 4; n++) for (int q = 0; q < 4; q++) acc[n][q] = 0.f;
    mfma16x64<HID>(A + (size_t)(tm + wid * 16) * HID, HID, W + (size_t)tn * HID, HID, acc, lane);
    int c = lane & 15, r0 = (lane >> 4) * 4;
    u16* Cw = C + (size_t)(tm + wid * 16) * 2048 + tn;
#pragma unroll
    for (int n = 0; n < 4; n++)
#pragma unroll
        for (int q = 0; q < 4; q++) {
            float x = acc[n][q] + bias[tn + n * 16 + c];
            Cw[(size_t)(r0 + q) * 2048 + n * 16 + c] = f2bf(fmaxf(x, 0.f));
        }
}

// ---------------- batched tail: fc2 (+bias, f32 out) ----------------
__global__ void __launch_bounds__(256) k_fc2b(const u16* __restrict__ A, const u16* __restrict__ W,
                       const float* __restrict__ bias, float* __restrict__ C) {
    int tn = blockIdx.x * 64, tm = blockIdx.y * 64;
    int wid = threadIdx.x >> 6, lane = threadIdx.x & 63;
    f32x4 acc[4];
#pragma unroll
    for (int n = 0; n < 4; n++) for (int q = 0; q < 4; q++) acc[n][q] = 0.f;
    mfma16x64<2048>(A + (size_t)(tm + wid * 16) * 2048, 2048, W + (size_t)tn * 2048, 2048, acc, lane);
    store_f32(C + (size_t)(tm + wid * 16) * VOC + tn, VOC, bias + tn, acc, lane);
}

// ---------------- logsumexp + target gather -> LP[t][b] ----------------
__global__ void __launch_bounds__(256) k_lse2(const float* __restrict__ part, const int* __restrict__ target,
                       int c0, float* __restrict__ LP) {
    int wid = threadIdx.x >> 6, lane = threadIdx.x & 63;
    int r = blockIdx.x * 4 + wid;
    const float* row = part + (size_t)r * VOC;
    float v[8];
#pragma unroll
    for (int e = 0; e < 8; e++) v[e] = row[e * 64 + lane];
    float m = v[0];
#pragma unroll
    for (int e = 1; e < 8; e++) m = fmaxf(m, v[e]);
    for (int o = 32; o > 0; o >>= 1) m = fmaxf(m, __shfl_xor(m, o));
    float s = 0.f;
#pragma unroll
    for (int e = 0; e < 8; e++) s += __expf(v[e] - m);
    for (int o = 32; o > 0; o >>= 1) s += __shfl_xor(s, o);
    int t = c0 + (r >> 8), b = r & 255;
    int tg = target[b * TLEN + t];
    float tv = 0.f;
#pragma unroll
    for (int e = 0; e < 8; e++) if (e * 64 + lane == tg) tv = v[e];
    for (int o = 32; o > 0; o >>= 1) tv += __shfl_xor(tv, o);
    if (lane == 0) LP[(size_t)t * BSZ + b] = tv - (m + logf(s));
}

// ---------------- final: out[b] = sum_t LP[t][b] ----------------
__global__ void k_out(const float* __restrict__ LP, float* __restrict__ out) {
    int b = threadIdx.x;
    float s = 0.f;
    for (int t = 0; t < TLEN; t++) s += LP[(size_t)t * BSZ + b];
    out[b] = s;
}

// ---------------- host ----------------
extern "C" void kernel_launch(void* const* d_in, const int* in_sizes, int n_in,
                              void* d_out, int out_size, void* d_ws, size_t ws_size,
                              hipStream_t stream) {
    const int*   target = (const int*)  d_in[0];
    const float* emb    = (const float*)d_in[1];
    const float* projW  = (const float*)d_in[2];
    const float* projb  = (const float*)d_in[3];
    const float* gWih   = (const float*)d_in[4];
    const float* gWhh   = (const float*)d_in[5];
    const float* gbih   = (const float*)d_in[6];
    const float* gbhh   = (const float*)d_in[7];
    const float* ln_s   = (const float*)d_in[8];
    const float* ln_b   = (const float*)d_in[9];
    const float* fc1W   = (const float*)d_in[10];
    const float* fc1b   = (const float*)d_in[11];
    const float* fc2W   = (const float*)d_in[12];
    const float* fc2b   = (const float*)d_in[13];
    float* out = (float*)d_out;

    char* ws = (char*)d_ws;
    size_t off = 0;
    auto alloc = [&](size_t bytes) { void* p = ws + off; off += (bytes + 511) & ~511ull; return p; };
    u16* emb_bf   = (u16*)alloc((size_t)VOC * EMB * 2);
    u16* projW_bf = (u16*)alloc((size_t)HID * EMB * 2);
    u16* Wih_bf   = (u16*)alloc((size_t)3 * B3H * HID * 2);
    u16* Whh_bf   = (u16*)alloc((size_t)3 * B3H * HID * 2);
    u16* X_all    = (u16*)alloc((size_t)TLEN * BSZ * HID * 2);   // becomes H2_all as loop consumes it
    float* h_f32  = (float*)alloc((size_t)2 * 3 * BSZ * HID * 4); // [slot][cell][B][H]
    u16*   h_bf   = (u16*)alloc((size_t)2 * 3 * BSZ * HID * 2);
    float* LP     = (float*)alloc((size_t)TLEN * BSZ * 4);
    float* giP    = (float*)alloc(3 * SLAB * 4);                  // 9.4 MB (loop only)
    float* ghP    = (float*)alloc(3 * SLAB * 4);                  // 9.4 MB (loop only)
    if (off > ws_size) return;

    // tail overlays (loop partials dead after loop; h_f32 dead after loop)
    u16*   fc1W_bf = (u16*)giP;                                   // 4 MB
    u16*   fc2W_bf = (u16*)((char*)giP + (size_t)2048 * HID * 2); // 2 MB
    u16*   a1c     = (u16*)ghP;                                   // 8 MB (CH=8)
    float* partc   = (float*)h_f32;                               // 4 MB (CH=8)

    auto cvt = [&](const float* s, u16* d, int n) {
        k_convert<<<dim3((n / 4 + 255) / 256), 256, 0, stream>>>(s, d, n);
    };
    cvt(emb,   emb_bf,   VOC * EMB);
    cvt(projW, projW_bf, HID * EMB);
    cvt(gWih,  Wih_bf,   3 * B3H * HID);
    cvt(gWhh,  Whh_bf,   3 * B3H * HID);
    hipMemsetAsync(h_f32, 0, (size_t)2 * 3 * BSZ * HID * 4, stream);
    hipMemsetAsync(h_bf,  0, (size_t)2 * 3 * BSZ * HID * 2, stream);

    // X_all[t*B+b] = emb[tok] @ projW^T + projb
    k_proj<<<dim3(HID / 64, (TLEN * BSZ) / 64), 256, 0, stream>>>(emb_bf, projW_bf, projb, target, X_all);

    // wavefront over (cell, t): wave wv handles cell c at t = wv - c
    for (int wv = 0; wv < TLEN + 2; wv++) {
        k_wgemm<<<dim3(B3H / 64, BSZ / 64, 6), 256, 0, stream>>>(wv, X_all, h_bf, Wih_bf, Whh_bf, giP, ghP);
        k_wew<<<dim3(BSZ / 4, 3), 256, 0, stream>>>(wv, giP, ghP, gbih, gbhh, h_f32, h_bf, X_all, ln_s, ln_b);
    }

    // tail: fc1 -> fc2 -> log-softmax over T in chunks of CH=8
    cvt(fc1W, fc1W_bf, 2048 * HID);
    cvt(fc2W, fc2W_bf, VOC * 2048);
    const int CH = 8;
    for (int c0 = 0; c0 < TLEN; c0 += CH) {
        int M = CH * BSZ;
        const u16* Ain = X_all + (size_t)c0 * BSZ * HID;   // H2 rows for steps [c0, c0+CH)
        k_fc1b<<<dim3(2048 / 64, M / 64), 256, 0, stream>>>(Ain, fc1W_bf, fc1b, a1c);
        k_fc2b<<<dim3(VOC / 64, M / 64), 256, 0, stream>>>(a1c, fc2W_bf, fc2b, partc);
        k_lse2<<<dim3(M / 4), 256, 0, stream>>>(partc, target, c0, LP);
    }
    k_out<<<1, 256, 0, stream>>>(LP, out);
}

// Round 6
// 11085.716 us; speedup vs baseline: 3.0575x; 1.3501x over previous
//
#include <hip/hip_runtime.h>
#include <stdint.h>

// ---------------- constants ----------------
#define HID   1024          // H
#define B3H   3072          // 3H
#define BSZ   256           // batch
#define TLEN  128           // seq len
#define VOC   512
#define EMB   512
#define SLAB  ((size_t)BSZ * B3H)    // one [256,3072] f32 slab (elements)

typedef unsigned short u16;
typedef short bf16x8 __attribute__((ext_vector_type(8)));
typedef float f32x4  __attribute__((ext_vector_type(4)));

__device__ __forceinline__ float bf2f(u16 u) {
    union { float f; uint32_t i; } c; c.i = ((uint32_t)u) << 16; return c.f;
}
__device__ __forceinline__ u16 f2bf(float f) {
    union { float f; uint32_t i; } c; c.f = f;
    uint32_t u = c.i;
    return (u16)((u + 0x7FFFu + ((u >> 16) & 1u)) >> 16);   // RNE
}
__device__ __forceinline__ float sigm(float x)  { return 1.f / (1.f + __expf(-x)); }
__device__ __forceinline__ float tanhf_(float x) {
    float e = __expf(-2.f * fabsf(x));
    float r = (1.f - e) / (1.f + e);
    return x < 0.f ? -r : r;
}

// ---------------- tiny utility kernels ----------------
__global__ void k_convert(const float* __restrict__ in, u16* __restrict__ out, int n) {
    int i = (blockIdx.x * 256 + threadIdx.x) * 4;
    if (i >= n) return;
    float4 f = *(const float4*)(in + i);
    uint32_t lo = (uint32_t)f2bf(f.x) | ((uint32_t)f2bf(f.y) << 16);
    uint32_t hi = (uint32_t)f2bf(f.z) | ((uint32_t)f2bf(f.w) << 16);
    uint2 p; p.x = lo; p.y = hi;
    *(uint2*)(out + i) = p;
}

// ---------------- MFMA tile helper (16x64 per wave) ----------------
template<int KLEN>
__device__ __forceinline__ void mfma16x64(const u16* __restrict__ Aw, int lda,
                                          const u16* __restrict__ Wt, int ldb,
                                          f32x4 acc[4], int lane) {
    const int r = lane & 15, g = lane >> 4;
    const u16* ap = Aw + (size_t)r * lda + g * 8;
    const u16* bp = Wt + (size_t)r * ldb + g * 8;
#pragma unroll 4
    for (int k = 0; k < KLEN; k += 32) {
        bf16x8 a = *(const bf16x8*)(ap + k);
#pragma unroll
        for (int n = 0; n < 4; n++) {
            bf16x8 b = *(const bf16x8*)(bp + (size_t)(n * 16) * ldb + k);
            acc[n] = __builtin_amdgcn_mfma_f32_16x16x32_bf16(a, b, acc[n], 0, 0, 0);
        }
    }
}
__device__ __forceinline__ void store_f32(float* Cw, int ldc, const float* bias,
                                          const f32x4 acc[4], int lane) {
    int c = lane & 15, r0 = (lane >> 4) * 4;
#pragma unroll
    for (int n = 0; n < 4; n++)
#pragma unroll
        for (int r = 0; r < 4; r++) {
            float x = acc[n][r] + (bias ? bias[n * 16 + c] : 0.f);
            Cw[(size_t)(r0 + r) * ldc + n * 16 + c] = x;
        }
}

// ---------------- proj: X_all[t*B+b] = emb[tok] @ projW^T + projb (bf16 out) ----------------
__global__ void __launch_bounds__(256) k_proj(const u16* __restrict__ emb_bf, const u16* __restrict__ projW_bf,
                       const float* __restrict__ projb, const int* __restrict__ target,
                       u16* __restrict__ X_all) {
    int tn = blockIdx.x * 64, tm = blockIdx.y * 64;
    int wid = threadIdx.x >> 6, lane = threadIdx.x & 63;
    int rr = lane & 15, g = lane >> 4;
    int rowg = tm + wid * 16 + rr;
    int t = rowg >> 8, b = rowg & 255;
    int tok = (t == 0) ? 0 : target[b * TLEN + t - 1];
    const u16* ap = emb_bf + (size_t)tok * EMB + g * 8;
    f32x4 acc[4];
#pragma unroll
    for (int n = 0; n < 4; n++) for (int q = 0; q < 4; q++) acc[n][q] = 0.f;
#pragma unroll 4
    for (int k = 0; k < EMB; k += 32) {
        bf16x8 a = *(const bf16x8*)(ap + k);
#pragma unroll
        for (int n = 0; n < 4; n++) {
            bf16x8 bb = *(const bf16x8*)(projW_bf + (size_t)(tn + n * 16 + rr) * EMB + g * 8 + k);
            acc[n] = __builtin_amdgcn_mfma_f32_16x16x32_bf16(a, bb, acc[n], 0, 0, 0);
        }
    }
    int c = lane & 15, r0 = (lane >> 4) * 4;
    u16* Cw = X_all + (size_t)(tm + wid * 16) * HID + tn;
#pragma unroll
    for (int n = 0; n < 4; n++)
#pragma unroll
        for (int q = 0; q < 4; q++)
            Cw[(size_t)(r0 + q) * HID + n * 16 + c] = f2bf(acc[n][q] + projb[tn + n * 16 + c]);
}

// ============== wavefront GEMM, XCD-pinned column strips ==============
// 288 blocks. xcd = blockIdx&7 owns 6 strips (384 cols) x 6 groups -> 4.7 MB
// of weights, L2-resident across all 130 launches. Block = 4 waves, each
// wave computes 64 rows x 64 cols (16 MFMA : 8 loads per K-step).
// groups g: 0..2 = gi_cell  (A = X[t] | h[c-1]),  3..5 = gh_cell (A = h[c])
__global__ void __launch_bounds__(256) k_wgemm(int wv,
    const u16* __restrict__ X_all, const u16* __restrict__ h_bf,
    const u16* __restrict__ Wih, const u16* __restrict__ Whh,
    float* __restrict__ giP, float* __restrict__ ghP) {
    int xcd = blockIdx.x & 7, q = blockIdx.x >> 3;   // q in [0,36)
    int g = q % 6, sl = q / 6;                       // group, local strip
    int cell = (g >= 3) ? g - 3 : g;
    bool isgh = (g >= 3);
    int t = wv - cell;
    if (t < 0 || t >= TLEN) return;
    int col0 = (xcd * 6 + sl) * 64;
    int rd = (wv + 1) & 1;
    const u16* A;
    if (isgh)            A = h_bf + (size_t)(rd * 3 + cell)     * BSZ * HID;
    else if (cell == 0)  A = X_all + (size_t)t * BSZ * HID;
    else                 A = h_bf + (size_t)(rd * 3 + cell - 1) * BSZ * HID;
    const u16* W = (isgh ? Whh : Wih) + (size_t)cell * B3H * HID + (size_t)col0 * HID;
    float*     C = (isgh ? ghP : giP) + (size_t)cell * SLAB + col0;

    int wid = threadIdx.x >> 6, lane = threadIdx.x & 63;
    int r = lane & 15, gk = lane >> 4;
    const u16* ap = A + (size_t)(wid * 64 + r) * HID + gk * 8;
    const u16* bp = W + (size_t)r * HID + gk * 8;

    f32x4 acc[4][4];
#pragma unroll
    for (int qr = 0; qr < 4; qr++)
#pragma unroll
        for (int n = 0; n < 4; n++)
#pragma unroll
            for (int e = 0; e < 4; e++) acc[qr][n][e] = 0.f;

#pragma unroll 2
    for (int k = 0; k < HID; k += 32) {
        bf16x8 a[4], b[4];
#pragma unroll
        for (int qr = 0; qr < 4; qr++) a[qr] = *(const bf16x8*)(ap + (size_t)(qr * 16) * HID + k);
#pragma unroll
        for (int n = 0; n < 4; n++)    b[n]  = *(const bf16x8*)(bp + (size_t)(n * 16) * HID + k);
#pragma unroll
        for (int qr = 0; qr < 4; qr++)
#pragma unroll
            for (int n = 0; n < 4; n++)
                acc[qr][n] = __builtin_amdgcn_mfma_f32_16x16x32_bf16(a[qr], b[n], acc[qr][n], 0, 0, 0);
    }
    // D frag: col = lane&15, row = (lane>>4)*4 + reg.  Nontemporal: consumed once by ew.
    int c = lane & 15, r0 = gk * 4;
#pragma unroll
    for (int qr = 0; qr < 4; qr++) {
        float* Cw = C + (size_t)(wid * 64 + qr * 16 + r0) * B3H;
#pragma unroll
        for (int n = 0; n < 4; n++)
#pragma unroll
            for (int e = 0; e < 4; e++)
                __builtin_nontemporal_store(acc[qr][n][e], Cw + (size_t)e * B3H + n * 16 + c);
    }
}

// ============== wavefront ew: 3 cells, 1 wave per batch row ==============
__global__ void __launch_bounds__(256) k_wew(int wv,
    const float* __restrict__ giP, const float* __restrict__ ghP,
    const float* __restrict__ bih_all, const float* __restrict__ bhh_all,
    float* __restrict__ h_f32, u16* __restrict__ h_bf, u16* __restrict__ X_all,
    const float* __restrict__ ln_s_all, const float* __restrict__ ln_b_all) {
    int cell = blockIdx.y;
    int t = wv - cell;
    if (t < 0 || t >= TLEN) return;
    int wid = threadIdx.x >> 6, lane = threadIdx.x & 63;
    int b = blockIdx.x * 4 + wid;
    int rd = (wv + 1) & 1, wr = wv & 1;

    const float* gi  = giP + (size_t)cell * SLAB + (size_t)b * B3H;
    const float* gh  = ghP + (size_t)cell * SLAB + (size_t)b * B3H;
    const float* bih = bih_all + cell * B3H;
    const float* bhh = bhh_all + cell * B3H;
    const float* lns = ln_s_all + cell * HID;
    const float* lnb = ln_b_all + cell * HID;
    const float* hprev = h_f32 + ((size_t)(rd * 3 + cell) * BSZ + b) * HID;
    float*       hout  = h_f32 + ((size_t)(wr * 3 + cell) * BSZ + b) * HID;
    u16*         hbout = h_bf  + ((size_t)(wr * 3 + cell) * BSZ + b) * HID;
    const float* xsrcf = (cell > 0) ? h_f32 + ((size_t)(rd * 3 + cell - 1) * BSZ + b) * HID : nullptr;
    const u16*   xsrcb = X_all + ((size_t)t * BSZ + b) * HID;

    float val[16], s = 0.f, s2 = 0.f;
#pragma unroll
    for (int e = 0; e < 4; e++) {
        int j = e * 256 + lane * 4;
        float gg[3][4], hh[3][4];
#pragma unroll
        for (int g = 0; g < 3; g++) {
            int o = g * HID + j;
            f32x4 a = __builtin_nontemporal_load((const f32x4*)(gi + o));
            float4 ab = *(const float4*)(bih + o);
            gg[g][0] = a[0] + ab.x; gg[g][1] = a[1] + ab.y; gg[g][2] = a[2] + ab.z; gg[g][3] = a[3] + ab.w;
            f32x4 h4 = __builtin_nontemporal_load((const f32x4*)(gh + o));
            float4 hb = *(const float4*)(bhh + o);
            hh[g][0] = h4[0] + hb.x; hh[g][1] = h4[1] + hb.y; hh[g][2] = h4[2] + hb.z; hh[g][3] = h4[3] + hb.w;
        }
        float4 hp = *(const float4*)(hprev + j);
        float hpv[4] = {hp.x, hp.y, hp.z, hp.w};
        float xv[4];
        if (cell == 0) {
            ushort4 u = *(const ushort4*)(xsrcb + j);
            xv[0] = bf2f(u.x); xv[1] = bf2f(u.y); xv[2] = bf2f(u.z); xv[3] = bf2f(u.w);
        } else {
            float4 x4 = *(const float4*)(xsrcf + j);
            xv[0] = x4.x; xv[1] = x4.y; xv[2] = x4.z; xv[3] = x4.w;
        }
#pragma unroll
        for (int q = 0; q < 4; q++) {
            float r = sigm(gg[0][q] + hh[0][q]);
            float z = sigm(gg[1][q] + hh[1][q]);
            float n = tanhf_(gg[2][q] + r * hh[2][q]);
            float v = (1.f - z) * n + z * hpv[q] + xv[q];
            val[e * 4 + q] = v; s += v; s2 += v * v;
        }
    }
#pragma unroll
    for (int o = 32; o > 0; o >>= 1) { s += __shfl_xor(s, o); s2 += __shfl_xor(s2, o); }
    float mu = s * (1.f / HID);
    float inv = rsqrtf(s2 * (1.f / HID) - mu * mu + 1e-5f);
#pragma unroll
    for (int e = 0; e < 4; e++) {
        int j = e * 256 + lane * 4;
        float4 sc = *(const float4*)(lns + j);
        float4 bi = *(const float4*)(lnb + j);
        float o0 = (val[e * 4 + 0] - mu) * inv * sc.x + bi.x;
        float o1 = (val[e * 4 + 1] - mu) * inv * sc.y + bi.y;
        float o2 = (val[e * 4 + 2] - mu) * inv * sc.z + bi.z;
        float o3 = (val[e * 4 + 3] - mu) * inv * sc.w + bi.w;
        float4 of; of.x = o0; of.y = o1; of.z = o2; of.w = o3;
        *(float4*)(hout + j) = of;
        u16 b0 = f2bf(o0), b1 = f2bf(o1), b2 = f2bf(o2), b3 = f2bf(o3);
        uint64_t packed = (uint64_t)b0 | ((uint64_t)b1 << 16) | ((uint64_t)b2 << 32) | ((uint64_t)b3 << 48);
        *(uint64_t*)(hbout + j) = packed;
        if (cell == 2) {
            // slot t consumed at wave t -> becomes H2_all; read only by tail, keep out of L2
            __builtin_nontemporal_store(packed, (uint64_t*)(X_all + ((size_t)t * BSZ + b) * HID + j));
        }
    }
}

// ---------------- batched tail: fc1 (relu, bf16 out) ----------------
__global__ void __launch_bounds__(256) k_fc1b(const u16* __restrict__ A, const u16* __restrict__ W,
                       const float* __restrict__ bias, u16* __restrict__ C) {
    int tn = blockIdx.x * 64, tm = blockIdx.y * 64;
    int wid = threadIdx.x >> 6, lane = threadIdx.x & 63;
    f32x4 acc[4];
#pragma unroll
    for (int n = 0; n < 4; n++) for (int q = 0; q < 4; q++) acc[n][q] = 0.f;
    mfma16x64<HID>(A + (size_t)(tm + wid * 16) * HID, HID, W + (size_t)tn * HID, HID, acc, lane);
    int c = lane & 15, r0 = (lane >> 4) * 4;
    u16* Cw = C + (size_t)(tm + wid * 16) * 2048 + tn;
#pragma unroll
    for (int n = 0; n < 4; n++)
#pragma unroll
        for (int q = 0; q < 4; q++) {
            float x = acc[n][q] + bias[tn + n * 16 + c];
            Cw[(size_t)(r0 + q) * 2048 + n * 16 + c] = f2bf(fmaxf(x, 0.f));
        }
}

// ---------------- batched tail: fc2 (+bias, f32 out) ----------------
__global__ void __launch_bounds__(256) k_fc2b(const u16* __restrict__ A, const u16* __restrict__ W,
                       const float* __restrict__ bias, float* __restrict__ C) {
    int tn = blockIdx.x * 64, tm = blockIdx.y * 64;
    int wid = threadIdx.x >> 6, lane = threadIdx.x & 63;
    f32x4 acc[4];
#pragma unroll
    for (int n = 0; n < 4; n++) for (int q = 0; q < 4; q++) acc[n][q] = 0.f;
    mfma16x64<2048>(A + (size_t)(tm + wid * 16) * 2048, 2048, W + (size_t)tn * 2048, 2048, acc, lane);
    store_f32(C + (size_t)(tm + wid * 16) * VOC + tn, VOC, bias + tn, acc, lane);
}

// ---------------- logsumexp + target gather -> LP[t][b] ----------------
__global__ void __launch_bounds__(256) k_lse2(const float* __restrict__ part, const int* __restrict__ target,
                       int c0, float* __restrict__ LP) {
    int wid = threadIdx.x >> 6, lane = threadIdx.x & 63;
    int r = blockIdx.x * 4 + wid;
    const float* row = part + (size_t)r * VOC;
    float v[8];
#pragma unroll
    for (int e = 0; e < 8; e++) v[e] = row[e * 64 + lane];
    float m = v[0];
#pragma unroll
    for (int e = 1; e < 8; e++) m = fmaxf(m, v[e]);
    for (int o = 32; o > 0; o >>= 1) m = fmaxf(m, __shfl_xor(m, o));
    float s = 0.f;
#pragma unroll
    for (int e = 0; e < 8; e++) s += __expf(v[e] - m);
    for (int o = 32; o > 0; o >>= 1) s += __shfl_xor(s, o);
    int t = c0 + (r >> 8), b = r & 255;
    int tg = target[b * TLEN + t];
    float tv = 0.f;
#pragma unroll
    for (int e = 0; e < 8; e++) if (e * 64 + lane == tg) tv = v[e];
    for (int o = 32; o > 0; o >>= 1) tv += __shfl_xor(tv, o);
    if (lane == 0) LP[(size_t)t * BSZ + b] = tv - (m + logf(s));
}

// ---------------- final: out[b] = sum_t LP[t][b] ----------------
__global__ void k_out(const float* __restrict__ LP, float* __restrict__ out) {
    int b = threadIdx.x;
    float s = 0.f;
    for (int t = 0; t < TLEN; t++) s += LP[(size_t)t * BSZ + b];
    out[b] = s;
}

// ---------------- host ----------------
extern "C" void kernel_launch(void* const* d_in, const int* in_sizes, int n_in,
                              void* d_out, int out_size, void* d_ws, size_t ws_size,
                              hipStream_t stream) {
    const int*   target = (const int*)  d_in[0];
    const float* emb    = (const float*)d_in[1];
    const float* projW  = (const float*)d_in[2];
    const float* projb  = (const float*)d_in[3];
    const float* gWih   = (const float*)d_in[4];
    const float* gWhh   = (const float*)d_in[5];
    const float* gbih   = (const float*)d_in[6];
    const float* gbhh   = (const float*)d_in[7];
    const float* ln_s   = (const float*)d_in[8];
    const float* ln_b   = (const float*)d_in[9];
    const float* fc1W   = (const float*)d_in[10];
    const float* fc1b   = (const float*)d_in[11];
    const float* fc2W   = (const float*)d_in[12];
    const float* fc2b   = (const float*)d_in[13];
    float* out = (float*)d_out;

    char* ws = (char*)d_ws;
    size_t off = 0;
    auto alloc = [&](size_t bytes) { void* p = ws + off; off += (bytes + 511) & ~511ull; return p; };
    u16* emb_bf   = (u16*)alloc((size_t)VOC * EMB * 2);
    u16* projW_bf = (u16*)alloc((size_t)HID * EMB * 2);
    u16* Wih_bf   = (u16*)alloc((size_t)3 * B3H * HID * 2);
    u16* Whh_bf   = (u16*)alloc((size_t)3 * B3H * HID * 2);
    u16* X_all    = (u16*)alloc((size_t)TLEN * BSZ * HID * 2);   // becomes H2_all as loop consumes it
    float* h_f32  = (float*)alloc((size_t)2 * 3 * BSZ * HID * 4); // [slot][cell][B][H]
    u16*   h_bf   = (u16*)alloc((size_t)2 * 3 * BSZ * HID * 2);
    float* LP     = (float*)alloc((size_t)TLEN * BSZ * 4);
    float* giP    = (float*)alloc(3 * SLAB * 4);                  // 9.4 MB (loop only)
    float* ghP    = (float*)alloc(3 * SLAB * 4);                  // 9.4 MB (loop only)
    if (off > ws_size) return;

    // tail overlays (loop partials dead after loop; h_f32 dead after loop)
    u16*   fc1W_bf = (u16*)giP;                                   // 4 MB
    u16*   fc2W_bf = (u16*)((char*)giP + (size_t)2048 * HID * 2); // 2 MB
    u16*   a1c     = (u16*)ghP;                                   // 8 MB (CH=8)
    float* partc   = (float*)h_f32;                               // 4 MB (CH=8)

    auto cvt = [&](const float* s, u16* d, int n) {
        k_convert<<<dim3((n / 4 + 255) / 256), 256, 0, stream>>>(s, d, n);
    };
    cvt(emb,   emb_bf,   VOC * EMB);
    cvt(projW, projW_bf, HID * EMB);
    cvt(gWih,  Wih_bf,   3 * B3H * HID);
    cvt(gWhh,  Whh_bf,   3 * B3H * HID);
    (void)hipMemsetAsync(h_f32, 0, (size_t)2 * 3 * BSZ * HID * 4, stream);
    (void)hipMemsetAsync(h_bf,  0, (size_t)2 * 3 * BSZ * HID * 2, stream);

    // X_all[t*B+b] = emb[tok] @ projW^T + projb
    k_proj<<<dim3(HID / 64, (TLEN * BSZ) / 64), 256, 0, stream>>>(emb_bf, projW_bf, projb, target, X_all);

    // wavefront over (cell, t): wave wv handles cell c at t = wv - c
    for (int wv = 0; wv < TLEN + 2; wv++) {
        k_wgemm<<<dim3(288), 256, 0, stream>>>(wv, X_all, h_bf, Wih_bf, Whh_bf, giP, ghP);
        k_wew<<<dim3(BSZ / 4, 3), 256, 0, stream>>>(wv, giP, ghP, gbih, gbhh, h_f32, h_bf, X_all, ln_s, ln_b);
    }

    // tail: fc1 -> fc2 -> log-softmax over T in chunks of CH=8
    cvt(fc1W, fc1W_bf, 2048 * HID);
    cvt(fc2W, fc2W_bf, VOC * 2048);
    const int CH = 8;
    for (int c0 = 0; c0 < TLEN; c0 += CH) {
        int M = CH * BSZ;
        const u16* Ain = X_all + (size_t)c0 * BSZ * HID;   // H2 rows for steps [c0, c0+CH)
        k_fc1b<<<dim3(2048 / 64, M / 64), 256, 0, stream>>>(Ain, fc1W_bf, fc1b, a1c);
        k_fc2b<<<dim3(VOC / 64, M / 64), 256, 0, stream>>>(a1c, fc2W_bf, fc2b, partc);
        k_lse2<<<dim3(M / 4), 256, 0, stream>>>(partc, target, c0, LP);
    }
    k_out<<<1, 256, 0, stream>>>(LP, out);
}

// Round 7
// 5231.591 us; speedup vs baseline: 6.4788x; 2.1190x over previous
//
#include <hip/hip_runtime.h>
#include <stdint.h>

// ---------------- constants ----------------
#define HID   1024          // H
#define B3H   3072          // 3H
#define BSZ   256           // batch
#define TLEN  128           // seq len
#define VOC   512
#define EMB   512
#define SLAB  ((size_t)BSZ * B3H)    // one [256,3072] f32 slab (elements)

typedef unsigned short u16;
typedef short bf16x8 __attribute__((ext_vector_type(8)));
typedef float f32x4  __attribute__((ext_vector_type(4)));

__device__ __forceinline__ float bf2f(u16 u) {
    union { float f; uint32_t i; } c; c.i = ((uint32_t)u) << 16; return c.f;
}
__device__ __forceinline__ u16 f2bf(float f) {
    union { float f; uint32_t i; } c; c.f = f;
    uint32_t u = c.i;
    return (u16)((u + 0x7FFFu + ((u >> 16) & 1u)) >> 16);   // RNE
}
__device__ __forceinline__ float sigm(float x)  { return 1.f / (1.f + __expf(-x)); }
__device__ __forceinline__ float tanhf_(float x) {
    float e = __expf(-2.f * fabsf(x));
    float r = (1.f - e) / (1.f + e);
    return x < 0.f ? -r : r;
}

// async global->LDS, 16B per lane (wave-uniform LDS base + lane*16)
__device__ __forceinline__ void gll16(const u16* g, u16* l) {
    __builtin_amdgcn_global_load_lds(
        (__attribute__((address_space(1))) void*)(u16*)g,
        (__attribute__((address_space(3))) void*)l, 16, 0, 0);
}

// stage one 128x32 bf16 tile (row-major src, stride ld) into linear LDS [128][32].
// 4 waves x 2 instr; instr covers 16 rows: lane l -> row l>>2, col-chunk l&3.
__device__ __forceinline__ void stage_tile(const u16* __restrict__ src, int ld,
                                           u16* __restrict__ lds, int wid, int lane) {
#pragma unroll
    for (int i = 0; i < 2; i++) {
        int row16 = wid * 2 + i;                       // 0..7 (16-row groups)
        const u16* g = src + (size_t)(row16 * 16 + (lane >> 2)) * ld + (lane & 3) * 8;
        u16* l = lds + row16 * 16 * 32;                // wave-uniform base
        gll16(g, l);
    }
}

// 128x128 x KTOT staged GEMM core: 4 waves, each 64x64 (acc[4][4] of 16x16 frags)
template<int KTOT>
__device__ __forceinline__ void gemm_tiles(const u16* __restrict__ A, const u16* __restrict__ W,
                                           f32x4 acc[4][4], int wid, int lane) {
    __shared__ u16 As[2][128 * 32], Ws[2][128 * 32];
    const int r = lane & 15, g8 = (lane >> 4) * 8;
    const int mq = wid & 1, nq = wid >> 1;
    int buf = 0;
    stage_tile(A, KTOT, As[0], wid, lane);
    stage_tile(W, KTOT, Ws[0], wid, lane);
    __syncthreads();
    for (int k0 = 0; k0 < KTOT; k0 += 32) {
        if (k0 + 32 < KTOT) {
            stage_tile(A + k0 + 32, KTOT, As[buf ^ 1], wid, lane);
            stage_tile(W + k0 + 32, KTOT, Ws[buf ^ 1], wid, lane);
        }
        bf16x8 a[4], b[4];
#pragma unroll
        for (int i = 0; i < 4; i++) a[i] = *(const bf16x8*)(As[buf] + (mq * 64 + i * 16 + r) * 32 + g8);
#pragma unroll
        for (int i = 0; i < 4; i++) b[i] = *(const bf16x8*)(Ws[buf] + (nq * 64 + i * 16 + r) * 32 + g8);
#pragma unroll
        for (int mi = 0; mi < 4; mi++)
#pragma unroll
            for (int ni = 0; ni < 4; ni++)
                acc[mi][ni] = __builtin_amdgcn_mfma_f32_16x16x32_bf16(a[mi], b[ni], acc[mi][ni], 0, 0, 0);
        __syncthreads();
        buf ^= 1;
    }
}

// ---------------- tiny utility kernels ----------------
__global__ void k_convert(const float* __restrict__ in, u16* __restrict__ out, int n) {
    int i = (blockIdx.x * 256 + threadIdx.x) * 4;
    if (i >= n) return;
    float4 f = *(const float4*)(in + i);
    uint32_t lo = (uint32_t)f2bf(f.x) | ((uint32_t)f2bf(f.y) << 16);
    uint32_t hi = (uint32_t)f2bf(f.z) | ((uint32_t)f2bf(f.w) << 16);
    uint2 p; p.x = lo; p.y = hi;
    *(uint2*)(out + i) = p;
}

// ---------------- proj: X_all[t*B+b] = emb[tok] @ projW^T + projb (bf16 out) ----------------
__global__ void __launch_bounds__(256) k_proj(const u16* __restrict__ emb_bf, const u16* __restrict__ projW_bf,
                       const float* __restrict__ projb, const int* __restrict__ target,
                       u16* __restrict__ X_all) {
    int tn = blockIdx.x * 64, tm = blockIdx.y * 64;
    int wid = threadIdx.x >> 6, lane = threadIdx.x & 63;
    int rr = lane & 15, g = lane >> 4;
    int rowg = tm + wid * 16 + rr;
    int t = rowg >> 8, b = rowg & 255;
    int tok = (t == 0) ? 0 : target[b * TLEN + t - 1];
    const u16* ap = emb_bf + (size_t)tok * EMB + g * 8;
    f32x4 acc[4];
#pragma unroll
    for (int n = 0; n < 4; n++) for (int q = 0; q < 4; q++) acc[n][q] = 0.f;
#pragma unroll 4
    for (int k = 0; k < EMB; k += 32) {
        bf16x8 a = *(const bf16x8*)(ap + k);
#pragma unroll
        for (int n = 0; n < 4; n++) {
            bf16x8 bb = *(const bf16x8*)(projW_bf + (size_t)(tn + n * 16 + rr) * EMB + g * 8 + k);
            acc[n] = __builtin_amdgcn_mfma_f32_16x16x32_bf16(a, bb, acc[n], 0, 0, 0);
        }
    }
    int c = lane & 15, r0 = (lane >> 4) * 4;
    u16* Cw = X_all + (size_t)(tm + wid * 16) * HID + tn;
#pragma unroll
    for (int n = 0; n < 4; n++)
#pragma unroll
        for (int q = 0; q < 4; q++)
            Cw[(size_t)(r0 + q) * HID + n * 16 + c] = f2bf(acc[n][q] + projb[tn + n * 16 + c]);
}

// ============== wavefront GEMM (staged 128^2): 6 groups x 2 Mtiles x 24 Ntiles ==============
// bid = g*48 + mt*24 + nt  (W-panel pair mt=0/1 differ by 24 == 0 mod 8 -> same XCD)
__global__ void __launch_bounds__(256) k_gstep(int wv,
    const u16* __restrict__ X_all, const u16* __restrict__ h_bf,
    const u16* __restrict__ Wih, const u16* __restrict__ Whh,
    float* __restrict__ giP, float* __restrict__ ghP) {
    int bid = blockIdx.x;
    int g = bid / 48, rem = bid % 48, mt = rem / 24, nt = rem % 24;
    int cell = g % 3; bool isgh = (g >= 3);
    int t = wv - cell;
    if (t < 0 || t >= TLEN) return;
    int rd = (wv + 1) & 1;
    const u16* A;
    if (isgh)            A = h_bf + (size_t)(rd * 3 + cell)     * BSZ * HID;
    else if (cell == 0)  A = X_all + (size_t)t * BSZ * HID;
    else                 A = h_bf + (size_t)(rd * 3 + cell - 1) * BSZ * HID;
    A += (size_t)(mt * 128) * HID;
    const u16* W = (isgh ? Whh : Wih) + (size_t)cell * B3H * HID + (size_t)(nt * 128) * HID;
    float*     C = (isgh ? ghP : giP) + (size_t)cell * SLAB + (size_t)(mt * 128) * B3H + nt * 128;

    int wid = threadIdx.x >> 6, lane = threadIdx.x & 63;
    f32x4 acc[4][4] = {};
    gemm_tiles<HID>(A, W, acc, wid, lane);
    int mq = wid & 1, nq = wid >> 1;
    int c = lane & 15, r0 = (lane >> 4) * 4;
#pragma unroll
    for (int mi = 0; mi < 4; mi++)
#pragma unroll
        for (int e = 0; e < 4; e++) {
            float* Cw = C + (size_t)(mq * 64 + mi * 16 + r0 + e) * B3H;
#pragma unroll
            for (int ni = 0; ni < 4; ni++)
                Cw[nq * 64 + ni * 16 + c] = acc[mi][ni][e];
        }
}

// ============== generic staged GEMM for the tail ==============
// EPI: 1 = bias+relu -> bf16 ; 2 = bias -> f32
template<int KTOT, int EPI>
__global__ void __launch_bounds__(256) k_gemm_s(const u16* __restrict__ A, const u16* __restrict__ W,
                                                const float* __restrict__ bias, void* __restrict__ Cout, int ldc) {
    int nt = blockIdx.x, mt = blockIdx.y;
    int wid = threadIdx.x >> 6, lane = threadIdx.x & 63;
    f32x4 acc[4][4] = {};
    gemm_tiles<KTOT>(A + (size_t)(mt * 128) * KTOT, W + (size_t)(nt * 128) * KTOT, acc, wid, lane);
    int mq = wid & 1, nq = wid >> 1;
    int c = lane & 15, r0 = (lane >> 4) * 4;
#pragma unroll
    for (int mi = 0; mi < 4; mi++)
#pragma unroll
        for (int e = 0; e < 4; e++) {
            size_t row = (size_t)(mt * 128 + mq * 64 + mi * 16 + r0 + e);
#pragma unroll
            for (int ni = 0; ni < 4; ni++) {
                int col = nt * 128 + nq * 64 + ni * 16 + c;
                float x = acc[mi][ni][e] + bias[col];
                if (EPI == 1) ((u16*)Cout)[row * ldc + col] = f2bf(fmaxf(x, 0.f));
                else          ((float*)Cout)[row * ldc + col] = x;
            }
        }
}

// ============== wavefront ew: 3 cells, 1 wave per batch row ==============
__global__ void __launch_bounds__(256) k_wew(int wv,
    const float* __restrict__ giP, const float* __restrict__ ghP,
    const float* __restrict__ bih_all, const float* __restrict__ bhh_all,
    float* __restrict__ h_f32, u16* __restrict__ h_bf, u16* __restrict__ X_all,
    const float* __restrict__ ln_s_all, const float* __restrict__ ln_b_all) {
    int cell = blockIdx.y;
    int t = wv - cell;
    if (t < 0 || t >= TLEN) return;
    int wid = threadIdx.x >> 6, lane = threadIdx.x & 63;
    int b = blockIdx.x * 4 + wid;
    int rd = (wv + 1) & 1, wr = wv & 1;

    const float* gi  = giP + (size_t)cell * SLAB + (size_t)b * B3H;
    const float* gh  = ghP + (size_t)cell * SLAB + (size_t)b * B3H;
    const float* bih = bih_all + cell * B3H;
    const float* bhh = bhh_all + cell * B3H;
    const float* lns = ln_s_all + cell * HID;
    const float* lnb = ln_b_all + cell * HID;
    const float* hprev = h_f32 + ((size_t)(rd * 3 + cell) * BSZ + b) * HID;
    float*       hout  = h_f32 + ((size_t)(wr * 3 + cell) * BSZ + b) * HID;
    u16*         hbout = h_bf  + ((size_t)(wr * 3 + cell) * BSZ + b) * HID;
    const float* xsrcf = (cell > 0) ? h_f32 + ((size_t)(rd * 3 + cell - 1) * BSZ + b) * HID : nullptr;
    const u16*   xsrcb = X_all + ((size_t)t * BSZ + b) * HID;

    float val[16], s = 0.f, s2 = 0.f;
#pragma unroll
    for (int e = 0; e < 4; e++) {
        int j = e * 256 + lane * 4;
        float gg[3][4], hh[3][4];
#pragma unroll
        for (int g = 0; g < 3; g++) {
            int o = g * HID + j;
            f32x4 a = __builtin_nontemporal_load((const f32x4*)(gi + o));
            float4 ab = *(const float4*)(bih + o);
            gg[g][0] = a[0] + ab.x; gg[g][1] = a[1] + ab.y; gg[g][2] = a[2] + ab.z; gg[g][3] = a[3] + ab.w;
            f32x4 h4 = __builtin_nontemporal_load((const f32x4*)(gh + o));
            float4 hb = *(const float4*)(bhh + o);
            hh[g][0] = h4[0] + hb.x; hh[g][1] = h4[1] + hb.y; hh[g][2] = h4[2] + hb.z; hh[g][3] = h4[3] + hb.w;
        }
        float4 hp = *(const float4*)(hprev + j);
        float hpv[4] = {hp.x, hp.y, hp.z, hp.w};
        float xv[4];
        if (cell == 0) {
            ushort4 u = *(const ushort4*)(xsrcb + j);
            xv[0] = bf2f(u.x); xv[1] = bf2f(u.y); xv[2] = bf2f(u.z); xv[3] = bf2f(u.w);
        } else {
            float4 x4 = *(const float4*)(xsrcf + j);
            xv[0] = x4.x; xv[1] = x4.y; xv[2] = x4.z; xv[3] = x4.w;
        }
#pragma unroll
        for (int q = 0; q < 4; q++) {
            float r = sigm(gg[0][q] + hh[0][q]);
            float z = sigm(gg[1][q] + hh[1][q]);
            float n = tanhf_(gg[2][q] + r * hh[2][q]);
            float v = (1.f - z) * n + z * hpv[q] + xv[q];
            val[e * 4 + q] = v; s += v; s2 += v * v;
        }
    }
#pragma unroll
    for (int o = 32; o > 0; o >>= 1) { s += __shfl_xor(s, o); s2 += __shfl_xor(s2, o); }
    float mu = s * (1.f / HID);
    float inv = rsqrtf(s2 * (1.f / HID) - mu * mu + 1e-5f);
#pragma unroll
    for (int e = 0; e < 4; e++) {
        int j = e * 256 + lane * 4;
        float4 sc = *(const float4*)(lns + j);
        float4 bi = *(const float4*)(lnb + j);
        float o0 = (val[e * 4 + 0] - mu) * inv * sc.x + bi.x;
        float o1 = (val[e * 4 + 1] - mu) * inv * sc.y + bi.y;
        float o2 = (val[e * 4 + 2] - mu) * inv * sc.z + bi.z;
        float o3 = (val[e * 4 + 3] - mu) * inv * sc.w + bi.w;
        float4 of; of.x = o0; of.y = o1; of.z = o2; of.w = o3;
        *(float4*)(hout + j) = of;
        u16 b0 = f2bf(o0), b1 = f2bf(o1), b2 = f2bf(o2), b3 = f2bf(o3);
        uint64_t packed = (uint64_t)b0 | ((uint64_t)b1 << 16) | ((uint64_t)b2 << 32) | ((uint64_t)b3 << 48);
        *(uint64_t*)(hbout + j) = packed;
        if (cell == 2) {
            __builtin_nontemporal_store(packed, (uint64_t*)(X_all + ((size_t)t * BSZ + b) * HID + j));
        }
    }
}

// ---------------- logsumexp + target gather -> LP[t][b] ----------------
__global__ void __launch_bounds__(256) k_lse2(const float* __restrict__ part, const int* __restrict__ target,
                       int c0, float* __restrict__ LP) {
    int wid = threadIdx.x >> 6, lane = threadIdx.x & 63;
    int r = blockIdx.x * 4 + wid;
    const float* row = part + (size_t)r * VOC;
    float v[8];
#pragma unroll
    for (int e = 0; e < 8; e++) v[e] = row[e * 64 + lane];
    float m = v[0];
#pragma unroll
    for (int e = 1; e < 8; e++) m = fmaxf(m, v[e]);
    for (int o = 32; o > 0; o >>= 1) m = fmaxf(m, __shfl_xor(m, o));
    float s = 0.f;
#pragma unroll
    for (int e = 0; e < 8; e++) s += __expf(v[e] - m);
    for (int o = 32; o > 0; o >>= 1) s += __shfl_xor(s, o);
    int t = c0 + (r >> 8), b = r & 255;
    int tg = target[b * TLEN + t];
    float tv = 0.f;
#pragma unroll
    for (int e = 0; e < 8; e++) if (e * 64 + lane == tg) tv = v[e];
    for (int o = 32; o > 0; o >>= 1) tv += __shfl_xor(tv, o);
    if (lane == 0) LP[(size_t)t * BSZ + b] = tv - (m + logf(s));
}

// ---------------- final: out[b] = sum_t LP[t][b] ----------------
__global__ void k_out(const float* __restrict__ LP, float* __restrict__ out) {
    int b = threadIdx.x;
    float s = 0.f;
    for (int t = 0; t < TLEN; t++) s += LP[(size_t)t * BSZ + b];
    out[b] = s;
}

// ---------------- host ----------------
extern "C" void kernel_launch(void* const* d_in, const int* in_sizes, int n_in,
                              void* d_out, int out_size, void* d_ws, size_t ws_size,
                              hipStream_t stream) {
    const int*   target = (const int*)  d_in[0];
    const float* emb    = (const float*)d_in[1];
    const float* projW  = (const float*)d_in[2];
    const float* projb  = (const float*)d_in[3];
    const float* gWih   = (const float*)d_in[4];
    const float* gWhh   = (const float*)d_in[5];
    const float* gbih   = (const float*)d_in[6];
    const float* gbhh   = (const float*)d_in[7];
    const float* ln_s   = (const float*)d_in[8];
    const float* ln_b   = (const float*)d_in[9];
    const float* fc1W   = (const float*)d_in[10];
    const float* fc1b   = (const float*)d_in[11];
    const float* fc2W   = (const float*)d_in[12];
    const float* fc2b   = (const float*)d_in[13];
    float* out = (float*)d_out;

    char* ws = (char*)d_ws;
    size_t off = 0;
    auto alloc = [&](size_t bytes) { void* p = ws + off; off += (bytes + 511) & ~511ull; return p; };
    u16* emb_bf   = (u16*)alloc((size_t)VOC * EMB * 2);
    u16* projW_bf = (u16*)alloc((size_t)HID * EMB * 2);
    u16* Wih_bf   = (u16*)alloc((size_t)3 * B3H * HID * 2);
    u16* Whh_bf   = (u16*)alloc((size_t)3 * B3H * HID * 2);
    u16* X_all    = (u16*)alloc((size_t)TLEN * BSZ * HID * 2);   // becomes H2_all as loop consumes it
    float* h_f32  = (float*)alloc((size_t)2 * 3 * BSZ * HID * 4); // [slot][cell][B][H]
    u16*   h_bf   = (u16*)alloc((size_t)2 * 3 * BSZ * HID * 2);
    float* LP     = (float*)alloc((size_t)TLEN * BSZ * 4);
    float* giP    = (float*)alloc(3 * SLAB * 4);                  // 9.4 MB (loop only)
    float* ghP    = (float*)alloc(3 * SLAB * 4);                  // 9.4 MB (loop only)
    if (off > ws_size) return;

    // tail overlays (loop partials dead after loop; h_f32 dead after loop)
    u16*   fc1W_bf = (u16*)giP;                                   // 4 MB
    u16*   fc2W_bf = (u16*)((char*)giP + (size_t)2048 * HID * 2); // 2 MB
    u16*   a1c     = (u16*)ghP;                                   // 8.4 MB (CH=8)
    float* partc   = (float*)h_f32;                               // 4.2 MB (CH=8)

    auto cvt = [&](const float* s, u16* d, int n) {
        k_convert<<<dim3((n / 4 + 255) / 256), 256, 0, stream>>>(s, d, n);
    };
    cvt(emb,   emb_bf,   VOC * EMB);
    cvt(projW, projW_bf, HID * EMB);
    cvt(gWih,  Wih_bf,   3 * B3H * HID);
    cvt(gWhh,  Whh_bf,   3 * B3H * HID);
    (void)hipMemsetAsync(h_f32, 0, (size_t)2 * 3 * BSZ * HID * 4, stream);
    (void)hipMemsetAsync(h_bf,  0, (size_t)2 * 3 * BSZ * HID * 2, stream);

    // X_all[t*B+b] = emb[tok] @ projW^T + projb
    k_proj<<<dim3(HID / 64, (TLEN * BSZ) / 64), 256, 0, stream>>>(emb_bf, projW_bf, projb, target, X_all);

    // wavefront over (cell, t): wave wv handles cell c at t = wv - c
    for (int wv = 0; wv < TLEN + 2; wv++) {
        k_gstep<<<dim3(288), 256, 0, stream>>>(wv, X_all, h_bf, Wih_bf, Whh_bf, giP, ghP);
        k_wew<<<dim3(BSZ / 4, 3), 256, 0, stream>>>(wv, giP, ghP, gbih, gbhh, h_f32, h_bf, X_all, ln_s, ln_b);
    }

    // tail: fc1 -> fc2 -> log-softmax over T in chunks of CH=8
    cvt(fc1W, fc1W_bf, 2048 * HID);
    cvt(fc2W, fc2W_bf, VOC * 2048);
    const int CH = 8;
    for (int c0 = 0; c0 < TLEN; c0 += CH) {
        int M = CH * BSZ;  // 2048 rows
        const u16* Ain = X_all + (size_t)c0 * BSZ * HID;   // H2 rows for steps [c0, c0+CH)
        k_gemm_s<HID, 1><<<dim3(2048 / 128, M / 128), 256, 0, stream>>>(Ain, fc1W_bf, fc1b, a1c, 2048);
        k_gemm_s<2048, 2><<<dim3(VOC / 128, M / 128), 256, 0, stream>>>(a1c, fc2W_bf, fc2b, partc, VOC);
        k_lse2<<<dim3(M / 4), 256, 0, stream>>>(partc, target, c0, LP);
    }
    k_out<<<1, 256, 0, stream>>>(LP, out);
}